// Round 1
// 156.339 us; speedup vs baseline: 1.1739x; 1.1739x over previous
//
#include <hip/hip_runtime.h>
#include <stdint.h>

#define N_NODES 8192
#define KPAD 272
#define OUTC 384

typedef __attribute__((ext_vector_type(8))) short bhalf8;
typedef __attribute__((ext_vector_type(16))) float f32x16;
typedef __attribute__((ext_vector_type(4))) float f32x4;

__device__ inline unsigned short f2bf_rne(float f) {
    unsigned u = __builtin_bit_cast(unsigned, f);
    u += 0x7FFFu + ((u >> 16) & 1u);
    return (unsigned short)(u >> 16);
}

__device__ inline bhalf8 mk8(unsigned a, unsigned b, unsigned c, unsigned d) {
    union { unsigned u[4]; bhalf8 v; } U;
    U.u[0] = a; U.u[1] = b; U.u[2] = c; U.u[3] = d;
    return U.v;
}

#define GLD_TO_LDS(gptr, lptr)                                                              \
    __builtin_amdgcn_global_load_lds((const __attribute__((address_space(1))) void*)(gptr), \
                                     (__attribute__((address_space(3))) void*)(lptr), 16, 0, 0)

// ---------------- prep: pack x (bf16, K-padded), WcatT, WrT, bcat ----------------
__global__ void k_prep(const float* __restrict__ landmarks, const float* __restrict__ features,
                       const float* __restrict__ Wi, const float* __restrict__ bi,
                       const float* __restrict__ Wj, const float* __restrict__ bj,
                       const float* __restrict__ Wk, const float* __restrict__ bk,
                       const float* __restrict__ Wr,
                       unsigned short* __restrict__ xb, unsigned short* __restrict__ WcatT,
                       unsigned short* __restrict__ WrT, float* __restrict__ bcat) {
    int idx = blockIdx.x * 256 + threadIdx.x;
    const int XB_N = N_NODES * KPAD;   // 2,228,224
    const int WC_N = OUTC * KPAD;      // 104,448
    const int WR_N = 256 * 128;        // 32,768
    if (idx < XB_N) {
        int i = idx / KPAD, kk = idx - i * KPAD;
        float v = 0.f;
        if (kk < 256) v = features[i * 256 + kk];
        else if (kk < 259) v = landmarks[i * 3 + (kk - 256)];
        xb[idx] = f2bf_rne(v);
        return;
    }
    idx -= XB_N;
    if (idx < WC_N) {
        int n = idx / KPAD, kk = idx - n * KPAD;
        int sel = n >> 7, d = n & 127;
        const float* W = (sel == 0) ? Wi : ((sel == 1) ? Wj : Wk);
        float v = 0.f;
        if (kk < 256) v = W[(kk + 3) * 128 + d];
        else if (kk < 259) v = W[(kk - 256) * 128 + d];
        WcatT[idx] = f2bf_rne(v);
        return;
    }
    idx -= WC_N;
    if (idx < WR_N) {
        int c = idx >> 7, d = idx & 127;
        WrT[idx] = f2bf_rne(Wr[d * 256 + c]);
        return;
    }
    idx -= WR_N;
    if (idx < OUTC) {
        float v = (idx < 128) ? bi[idx] : ((idx < 256) ? bj[idx - 128] : bk[idx - 256]);
        bcat[idx] = v;
    }
}

// ---------------- k1: projections f = xb @ WcatT^T(+bias) -> fi, fj, fkT ----------------
__global__ __launch_bounds__(256) void k_proj(const unsigned short* __restrict__ xb,
                                              const unsigned short* __restrict__ WcatT,
                                              const float* __restrict__ bcat,
                                              unsigned short* __restrict__ fi,
                                              unsigned short* __restrict__ fj,
                                              unsigned short* __restrict__ fkT) {
    const int tid = threadIdx.x;
    const int w = tid >> 6, l = tid & 63, h = l >> 5, ln = l & 31;
    const int i0 = blockIdx.x * 32;
    f32x16 acc[3] = {};
#pragma unroll
    for (int s = 0; s < 17; ++s) {
        bhalf8 a = *(const bhalf8*)(xb + (size_t)(i0 + ln) * KPAD + s * 16 + h * 8);
#pragma unroll
        for (int t = 0; t < 3; ++t) {
            int n = 96 * w + 32 * t + ln;
            bhalf8 b = *(const bhalf8*)(WcatT + (size_t)n * KPAD + s * 16 + h * 8);
            acc[t] = __builtin_amdgcn_mfma_f32_32x32x16_bf16(a, b, acc[t], 0, 0, 0);
        }
    }
#pragma unroll
    for (int t = 0; t < 3; ++t) {
        int n = 96 * w + 32 * t + ln;
        int sel = n >> 7, d = n & 127;
        float bias = bcat[n];
#pragma unroll
        for (int q = 0; q < 4; ++q) {
            int ib = i0 + 8 * q + 4 * h;
            if (sel < 2) {
                unsigned short* dst = sel ? fj : fi;
#pragma unroll
                for (int r = 0; r < 4; ++r)
                    dst[(size_t)(ib + r) * 128 + d] = f2bf_rne(acc[t][4 * q + r] + bias);
            } else {
                ushort4 pk;
                pk.x = f2bf_rne(acc[t][4 * q + 0] + bias);
                pk.y = f2bf_rne(acc[t][4 * q + 1] + bias);
                pk.z = f2bf_rne(acc[t][4 * q + 2] + bias);
                pk.w = f2bf_rne(acc[t][4 * q + 3] + bias);
                *(ushort4*)(fkT + (size_t)d * N_NODES + ib) = pk;
            }
        }
    }
}

// ---------------- k2: fused sigmoid-attention, double-buffered 64-j chunks ----------------
// Waves: w = ih*2 + jh.  Wave (ih,jh) computes the [jh*32..+31] x [ih*32..+31] quadrant of
// each 64x64 S^T chunk, keeps PV partials num[128d][32i] over its jh half of the j-quarter.
__global__ __launch_bounds__(256, 2) void k_attn(const unsigned short* __restrict__ fi,
                                                 const unsigned short* __restrict__ fj,
                                                 const unsigned short* __restrict__ fkT,
                                                 float* __restrict__ num_part,
                                                 float* __restrict__ den_part) {
    __shared__ __align__(16) char smem[65536];
    char* const fjb0 = smem;             // [64 j][128 k] bf16, 16B chunks ^ (row&15), 16 KB
    char* const fkb0 = smem + 16384;     // [128 d][64 j] bf16, 16B chunks ^ (row&7),  16 KB
    char* const fjb1 = smem + 32768;
    char* const fkb1 = smem + 49152;

    const int tid = threadIdx.x;
    const int w = tid >> 6, l = tid & 63, h = l >> 5, ln = l & 31;
    const int ih = w >> 1, jh = w & 1;
    const int rt = blockIdx.x & 127, jq = blockIdx.x >> 7;
    const int i0 = rt * 64;
    const int jbase = jq * 2048;

    const int rsub = l >> 4, cph = l & 15;    // fj staging: 256B rows, 16 chunks
    const int rsub8 = l >> 3, cph8 = l & 7;   // fk staging: 128B rows, 8 chunks

    // hoist fi B-fragments for this wave's 32-i block (32 VGPRs), reused across all j
    bhalf8 bfi[8];
#pragma unroll
    for (int s = 0; s < 8; ++s)
        bfi[s] = *(const bhalf8*)(fi + (size_t)(i0 + ih * 32 + ln) * 128 + s * 16 + h * 8);

    f32x16 acc[4] = {};   // numT partials: [d-tile 0..3][wave's 32 i], over wave's jh half
    float dacc = 0.f;

    auto STAGE = [&](char* fjd, char* fkd, int J0) {
#pragma unroll
        for (int q = 0; q < 4; ++q) {
            int r = w * 16 + q * 4 + rsub;
            int c = cph ^ (r & 15);
            GLD_TO_LDS(fj + (size_t)(J0 + r) * 128 + c * 8, fjd + (w * 16 + q * 4) * 256);
        }
#pragma unroll
        for (int q = 0; q < 4; ++q) {
            int r = w * 32 + q * 8 + rsub8;
            int c = cph8 ^ (r & 7);
            GLD_TO_LDS(fkT + (size_t)r * N_NODES + J0 + c * 8, fkd + (w * 32 + q * 8) * 128);
        }
    };

    auto COMPUTE = [&](const char* fjbuf, const char* fkbuf) {
        // S^T quadrant = fj[jh half] @ fi[ih half]^T
        f32x16 st = {};
        const int jrow = jh * 32 + ln;
#pragma unroll
        for (int s = 0; s < 8; ++s) {
            int c = (s * 2 + h) ^ (jrow & 15);
            bhalf8 af = *(const bhalf8*)(fjbuf + jrow * 256 + c * 16);
            st = __builtin_amdgcn_mfma_f32_32x32x16_bf16(af, bfi[s], st, 0, 0, 0);
        }
        // sigmoid + denom accumulate + pack consecutive-j pairs to bf16
        unsigned p[8], xw[8];
#pragma unroll
        for (int q = 0; q < 8; ++q) {
            float x0 = __builtin_amdgcn_rcpf(1.f + __builtin_amdgcn_exp2f(st[2 * q] * -1.44269504f));
            float x1 = __builtin_amdgcn_rcpf(1.f + __builtin_amdgcn_exp2f(st[2 * q + 1] * -1.44269504f));
            dacc += x0;
            dacc += x1;
            p[q] = __builtin_amdgcn_perm(__builtin_bit_cast(unsigned, x1),
                                         __builtin_bit_cast(unsigned, x0), 0x07060302u);
        }
#pragma unroll
        for (int q = 0; q < 8; ++q) xw[q] = (unsigned)__shfl_xor((int)p[q], 32, 64);
        // assemble P^T B-operand fragments (k = j_local within the wave's 32-j slice)
        bhalf8 fb[2];
        if (h == 0) {
            fb[0] = mk8(p[0], p[1], xw[0], xw[1]);
            fb[1] = mk8(p[4], p[5], xw[4], xw[5]);
        } else {
            fb[0] = mk8(xw[2], xw[3], p[2], p[3]);
            fb[1] = mk8(xw[6], xw[7], p[6], p[7]);
        }
        // PV: numT[d][i] += fkT[d][j-slice] * P^T[j-slice][i]
#pragma unroll
        for (int m4 = 0; m4 < 4; ++m4) {
            int row = m4 * 32 + ln;
#pragma unroll
            for (int s2 = 0; s2 < 2; ++s2) {
                int c = (jh * 4 + s2 * 2 + h) ^ (row & 7);
                bhalf8 af = *(const bhalf8*)(fkbuf + row * 128 + c * 16);
                acc[m4] = __builtin_amdgcn_mfma_f32_32x32x16_bf16(af, fb[s2], acc[m4], 0, 0, 0);
            }
        }
    };

    // 2-phase pipeline: stage next chunk before computing current; single vmcnt-drain
    // barrier per chunk, placed AFTER compute so load latency hides under MFMA+sigmoid.
    STAGE(fjb0, fkb0, jbase);
    __syncthreads();
#pragma unroll 1
    for (int mt = 0; mt < 32; mt += 2) {
        STAGE(fjb1, fkb1, jbase + (mt + 1) * 64);
        COMPUTE(fjb0, fkb0);
        __syncthreads();
        if (mt + 2 < 32) STAGE(fjb0, fkb0, jbase + (mt + 2) * 64);
        COMPUTE(fjb1, fkb1);
        __syncthreads();
    }

    // denom: fold lane l <-> l^32 (h halves), stash per wave
    dacc += __shfl_xor(dacc, 32, 64);
    float* denb = (float*)(smem + 40960);   // 128 floats, disjoint from reduce buf
    if (h == 0) denb[w * 32 + ln] = dacc;

    // num reduce: jh=0 waves write [64 i][128 d] (pad 132), jh=1 waves add
    float* buf = (float*)smem;
    if (jh == 0) {
#pragma unroll
        for (int m4 = 0; m4 < 4; ++m4)
#pragma unroll
            for (int q = 0; q < 4; ++q) {
                f32x4 v = {acc[m4][4 * q + 0], acc[m4][4 * q + 1],
                           acc[m4][4 * q + 2], acc[m4][4 * q + 3]};
                *(f32x4*)(buf + (ih * 32 + ln) * 132 + m4 * 32 + 8 * q + 4 * h) = v;
            }
    }
    __syncthreads();
    if (jh == 1) {
#pragma unroll
        for (int m4 = 0; m4 < 4; ++m4)
#pragma unroll
            for (int q = 0; q < 4; ++q) {
                float* p4 = buf + (ih * 32 + ln) * 132 + m4 * 32 + 8 * q + 4 * h;
                f32x4 old = *(f32x4*)p4;
                f32x4 v = {acc[m4][4 * q + 0], acc[m4][4 * q + 1],
                           acc[m4][4 * q + 2], acc[m4][4 * q + 3]};
                *(f32x4*)p4 = old + v;
            }
    }
    __syncthreads();
#pragma unroll
    for (int e = 0; e < 8; ++e) {
        int v = e * 256 + tid;                 // 2048 float4s = 64 i x 32
        int iloc = v >> 5, d4 = (v & 31) * 4;
        *(f32x4*)(num_part + ((size_t)jq * N_NODES + i0 + iloc) * 128 + d4) =
            *(const f32x4*)(buf + iloc * 132 + d4);
    }
    if (tid < 64) {
        den_part[(size_t)jq * N_NODES + i0 + tid] =
            denb[(tid >> 5) * 64 + (tid & 31)] + denb[(tid >> 5) * 64 + 32 + (tid & 31)];
    }
}

// ---------------- k2b: t = (sum num)/(sum den) -> bf16 ----------------
__global__ void k_comb(const float* __restrict__ num_part, const float* __restrict__ den_part,
                       unsigned short* __restrict__ t) {
    int f = blockIdx.x * 256 + threadIdx.x;   // 262144 float4 groups
    int i = f >> 5, d4 = (f & 31) * 4;
    f32x4 s = {};
    float ds = 0.f;
#pragma unroll
    for (int q = 0; q < 4; ++q) {
        s += *(const f32x4*)(num_part + (size_t)(q * N_NODES + i) * 128 + d4);
        ds += den_part[(size_t)q * N_NODES + i];
    }
    float inv = 1.0f / ds;
    ushort4 pk;
    pk.x = f2bf_rne(s.x * inv);
    pk.y = f2bf_rne(s.y * inv);
    pk.z = f2bf_rne(s.z * inv);
    pk.w = f2bf_rne(s.w * inv);
    *(ushort4*)(t + (size_t)i * 128 + d4) = pk;
}

// ---------------- k3: out = t @ Wr + br + features ----------------
__global__ __launch_bounds__(256) void k_out(const unsigned short* __restrict__ t,
                                             const unsigned short* __restrict__ WrT,
                                             const float* __restrict__ br,
                                             const float* __restrict__ features,
                                             float* __restrict__ out) {
    __shared__ __align__(16) char smem[65536];
    const int tid = threadIdx.x, w = tid >> 6, l = tid & 63, h = l >> 5, ln = l & 31;
    const int i0 = blockIdx.x * 32;
    {
        int rsub = l >> 4, cph = l & 15;
#pragma unroll
        for (int q = 0; q < 16; ++q) {
            int r = w * 64 + q * 4 + rsub;
            int c = cph ^ (r & 15);
            GLD_TO_LDS(WrT + (size_t)r * 128 + c * 8, (char*)smem + (w * 64 + q * 4) * 256);
        }
    }
    __syncthreads();
    f32x16 acc[2] = {};
#pragma unroll
    for (int s = 0; s < 8; ++s) {
        bhalf8 af = *(const bhalf8*)(t + (size_t)(i0 + ln) * 128 + s * 16 + h * 8);
#pragma unroll
        for (int nt = 0; nt < 2; ++nt) {
            int row = w * 64 + nt * 32 + ln;
            int c = (s * 2 + h) ^ (row & 15);
            bhalf8 bf = *(const bhalf8*)((char*)smem + row * 256 + c * 16);
            acc[nt] = __builtin_amdgcn_mfma_f32_32x32x16_bf16(af, bf, acc[nt], 0, 0, 0);
        }
    }
#pragma unroll
    for (int nt = 0; nt < 2; ++nt) {
        int cc = w * 64 + nt * 32 + ln;
        float bias = br[cc];
#pragma unroll
        for (int q = 0; q < 4; ++q) {
#pragma unroll
            for (int r = 0; r < 4; ++r) {
                int i = i0 + 8 * q + 4 * h + r;
                out[(size_t)i * 256 + cc] = acc[nt][4 * q + r] + bias + features[(size_t)i * 256 + cc];
            }
        }
    }
}

extern "C" void kernel_launch(void* const* d_in, const int* in_sizes, int n_in,
                              void* d_out, int out_size, void* d_ws, size_t ws_size,
                              hipStream_t stream) {
    const float* landmarks = (const float*)d_in[0];
    const float* features  = (const float*)d_in[1];
    const float* Wi = (const float*)d_in[2];
    const float* bi = (const float*)d_in[3];
    const float* Wj = (const float*)d_in[4];
    const float* bj = (const float*)d_in[5];
    const float* Wk = (const float*)d_in[6];
    const float* bk = (const float*)d_in[7];
    const float* Wr = (const float*)d_in[8];
    const float* br = (const float*)d_in[9];

    char* ws = (char*)d_ws;
    unsigned short* xb      = (unsigned short*)(ws + 0);         // 8192x272 bf16
    unsigned short* WcatT   = (unsigned short*)(ws + 4456448);   // 384x272 bf16
    unsigned short* WrT     = (unsigned short*)(ws + 4665344);   // 256x128 bf16
    float*          bcat    = (float*)(ws + 4730880);            // 384 f32
    unsigned short* fi      = (unsigned short*)(ws + 4732416);   // 8192x128 bf16
    unsigned short* fjp     = (unsigned short*)(ws + 6829568);   // 8192x128 bf16
    unsigned short* fkT     = (unsigned short*)(ws + 8926720);   // 128x8192 bf16
    float*          num_part= (float*)(ws + 11023872);           // 4x8192x128 f32
    float*          den_part= (float*)(ws + 27801088);           // 4x8192 f32
    unsigned short* t       = (unsigned short*)(ws + 27932160);  // 8192x128 bf16

    float* out = (float*)d_out;

    hipLaunchKernelGGL(k_prep, dim3(9242), dim3(256), 0, stream,
                       landmarks, features, Wi, bi, Wj, bj, Wk, bk, Wr, xb, WcatT, WrT, bcat);
    hipLaunchKernelGGL(k_proj, dim3(256), dim3(256), 0, stream, xb, WcatT, bcat, fi, fjp, fkT);
    hipLaunchKernelGGL(k_attn, dim3(512), dim3(256), 0, stream, fi, fjp, fkT, num_part, den_part);
    hipLaunchKernelGGL(k_comb, dim3(1024), dim3(256), 0, stream, num_part, den_part, t);
    hipLaunchKernelGGL(k_out, dim3(256), dim3(256), 0, stream, t, WrT, br, features, out);
}